// Round 2
// baseline (11930.840 us; speedup 1.0000x reference)
//
#include <hip/hip_runtime.h>
#include <cstddef>

#define LRELU(y) ((y) >= 0.f ? (y) : 0.3f * (y))

// ---------------------------------------------------------------------------
// Pad (C,32,64) -> (C,34,66): reflect in H (row -1 = row 1, row 32 = row 30),
// circular in W (col -1 = col 63, col 64 = col 0). Matches reference _pad.
// ---------------------------------------------------------------------------
__global__ __launch_bounds__(256) void pad_rw(const float* __restrict__ in,
                                              float* __restrict__ out) {
    int c = blockIdx.y;
    int p = blockIdx.x * blockDim.x + threadIdx.x;
    if (p >= 34 * 66) return;
    int i = p / 66, j = p % 66;
    int h = i - 1;
    h = (h == -1) ? 1 : (h == 32 ? 30 : h);
    int w = (j - 1) & 63;  // j-1 in [-1,64]: -1->63, 64->0, else j-1
    out[(size_t)c * (34 * 66) + p] = in[(size_t)c * 2048 + h * 64 + w];
}

// ---------------------------------------------------------------------------
// Direct VALID 3x3 conv + bias + LeakyReLU(0.3).
// One thread = 4 horizontally adjacent output pixels of one cout.
// blockIdx.y = cout -> weight addresses wave-uniform (scalar loads).
// Boundary quads clamp ox0 to Wout-4: overlapping threads write identical
// values; all loads stay in-bounds because (Wout-1)*S+2 == Win-1 (VALID).
// ---------------------------------------------------------------------------
template <int S>
__global__ __launch_bounds__(256) void conv3x3(const float* __restrict__ X,
                                               const float* __restrict__ W,
                                               const float* __restrict__ B,
                                               float* __restrict__ Y,
                                               int Cin, int Hin, int Win,
                                               int Hout, int Wout) {
    const int cout = blockIdx.y;
    const int qpr = (Wout + 3) >> 2;
    const int nq = Hout * qpr;
    int q = blockIdx.x * blockDim.x + threadIdx.x;
    if (q >= nq) return;
    int oy = q / qpr;
    int ox0 = (q - oy * qpr) * 4;
    if (ox0 > Wout - 4) ox0 = Wout - 4;

    float acc[4] = {0.f, 0.f, 0.f, 0.f};
    const float* wp = W + (size_t)cout * Cin * 9;
    const float* xp = X + (size_t)(oy * S) * Win + ox0 * S;

#pragma unroll 2
    for (int ci = 0; ci < Cin; ++ci) {
        float w[9];
#pragma unroll
        for (int t = 0; t < 9; ++t) w[t] = wp[t];
        wp += 9;
        const float* xr = xp + (size_t)ci * Hin * Win;
#pragma unroll
        for (int dy = 0; dy < 3; ++dy) {
            const float* r = xr + dy * Win;
#pragma unroll
            for (int p = 0; p < 4; ++p)
#pragma unroll
                for (int dx = 0; dx < 3; ++dx)
                    acc[p] += r[p * S + dx] * w[dy * 3 + dx];
        }
    }

    float b = B[cout];
    float* yp = Y + (size_t)cout * Hout * Wout + (size_t)oy * Wout + ox0;
#pragma unroll
    for (int p = 0; p < 4; ++p) {
        float y = acc[p] + b;
        yp[p] = LRELU(y);
    }
}

// ---------------------------------------------------------------------------
// scores^T: sT[m][n] = sum_c Q[c][n] * K[c][m]   (Q: 256x2048, K: 256x65)
// ---------------------------------------------------------------------------
__global__ __launch_bounds__(256) void qk_scores(const float* __restrict__ Q,
                                                 const float* __restrict__ K,
                                                 float* __restrict__ ST) {
    int m = blockIdx.y;
    int n = blockIdx.x * blockDim.x + threadIdx.x;
    float acc = 0.f;
    for (int c = 0; c < 256; ++c)
        acc += Q[c * 2048 + n] * K[c * 65 + m];
    ST[(size_t)m * 2048 + n] = acc;
}

// ---------------------------------------------------------------------------
// Softmax over the n axis (2048) for each m. One wave per m.
// BT[m][n] = exp(sT[m][n]-max_n)/sum_n
// ---------------------------------------------------------------------------
__global__ __launch_bounds__(64) void softmax_n(const float* __restrict__ ST,
                                                float* __restrict__ BT) {
    int m = blockIdx.x;
    int lane = threadIdx.x;
    const float* s = ST + (size_t)m * 2048;
    float mx = -1e30f;
    for (int i = lane; i < 2048; i += 64) mx = fmaxf(mx, s[i]);
#pragma unroll
    for (int o = 32; o > 0; o >>= 1) mx = fmaxf(mx, __shfl_xor(mx, o, 64));
    float sum = 0.f;
    for (int i = lane; i < 2048; i += 64) sum += expf(s[i] - mx);
#pragma unroll
    for (int o = 32; o > 0; o >>= 1) sum += __shfl_xor(sum, o, 64);
    float inv = 1.f / sum;
    float* b = BT + (size_t)m * 2048;
    for (int i = lane; i < 2048; i += 64) b[i] = expf(s[i] - mx) * inv;
}

// ---------------------------------------------------------------------------
// o[v][n] = sum_m V[v][m] * BT[m][n]   (V: 1024x65, BT: 65x2048)
// ---------------------------------------------------------------------------
__global__ __launch_bounds__(128) void attn_o(const float* __restrict__ V,
                                              const float* __restrict__ BT,
                                              float* __restrict__ O) {
    int v = blockIdx.y;
    int n4 = (blockIdx.x * blockDim.x + threadIdx.x) * 4;
    float4 acc = {0.f, 0.f, 0.f, 0.f};
    for (int m = 0; m < 65; ++m) {
        float vv = V[v * 65 + m];
        float4 bb = *(const float4*)(BT + (size_t)m * 2048 + n4);
        acc.x += vv * bb.x;
        acc.y += vv * bb.y;
        acc.z += vv * bb.z;
        acc.w += vv * bb.w;
    }
    *(float4*)(O + (size_t)v * 2048 + n4) = acc;
}

// ---------------------------------------------------------------------------
// Final 1x1 conv: Y[co][n] = pb[co] + sum_ci pw[co][ci] * X[ci][n]
// ---------------------------------------------------------------------------
__global__ __launch_bounds__(128) void conv1x1(const float* __restrict__ X,
                                               const float* __restrict__ W,
                                               const float* __restrict__ B,
                                               float* __restrict__ Y) {
    int co = blockIdx.y;
    int n4 = (blockIdx.x * blockDim.x + threadIdx.x) * 4;
    float4 acc = {0.f, 0.f, 0.f, 0.f};
    const float* wp = W + (size_t)co * 1024;
    for (int ci = 0; ci < 1024; ++ci) {
        float w = wp[ci];
        float4 x = *(const float4*)(X + (size_t)ci * 2048 + n4);
        acc.x += w * x.x;
        acc.y += w * x.y;
        acc.z += w * x.z;
        acc.w += w * x.w;
    }
    float b = B[co];
    float4 r = {acc.x + b, acc.y + b, acc.z + b, acc.w + b};
    *(float4*)(Y + (size_t)co * 2048 + n4) = r;
}

// ---------------------------------------------------------------------------
extern "C" void kernel_launch(void* const* d_in, const int* in_sizes, int n_in,
                              void* d_out, int out_size, void* d_ws, size_t ws_size,
                              hipStream_t stream) {
    (void)in_sizes; (void)n_in; (void)out_size; (void)ws_size;
    const float* x   = (const float*)d_in[0];
    const float* qw1 = (const float*)d_in[1];
    const float* qb1 = (const float*)d_in[2];
    const float* qw2 = (const float*)d_in[3];
    const float* qb2 = (const float*)d_in[4];
    const float* qw3 = (const float*)d_in[5];
    const float* qb3 = (const float*)d_in[6];
    const float* kw1 = (const float*)d_in[7];
    const float* kb1 = (const float*)d_in[8];
    const float* kw2 = (const float*)d_in[9];
    const float* kb2 = (const float*)d_in[10];
    const float* kw3 = (const float*)d_in[11];
    const float* kb3 = (const float*)d_in[12];
    const float* vw1 = (const float*)d_in[13];
    const float* vb1 = (const float*)d_in[14];
    const float* vw2 = (const float*)d_in[15];
    const float* vb2 = (const float*)d_in[16];
    const float* vw3 = (const float*)d_in[17];
    const float* vb3 = (const float*)d_in[18];
    const float* pw  = (const float*)d_in[19];
    const float* pb  = (const float*)d_in[20];
    float* out = (float*)d_out;

    float* ws = (float*)d_ws;
    size_t off = 0;
    auto alloc = [&](size_t n) { float* p = ws + off; off += n; return p; };
    float* xpad = alloc((size_t)2048 * 34 * 66);
    float* q1   = alloc((size_t)1024 * 2048);
    float* q1p  = alloc((size_t)1024 * 34 * 66);
    float* q2   = alloc((size_t)256 * 2048);
    float* q2p  = alloc((size_t)256 * 34 * 66);
    float* q3   = alloc((size_t)256 * 2048);
    float* k1   = alloc((size_t)1024 * 465);
    float* k2   = alloc((size_t)256 * 105);
    float* k3   = alloc((size_t)256 * 65);
    float* v1   = alloc((size_t)1024 * 465);
    float* v2   = alloc((size_t)1024 * 105);
    float* v3   = alloc((size_t)1024 * 65);
    float* sT   = alloc((size_t)65 * 2048);
    float* bT   = alloc((size_t)65 * 2048);
    float* o    = alloc((size_t)1024 * 2048);

    dim3 b256(256);
    auto conv = [&](const float* X, const float* W, const float* B, float* Y,
                    int Cin, int Cout, int Hin, int Win, int Hout, int Wout, int S) {
        int qpr = (Wout + 3) >> 2;
        int nq = Hout * qpr;
        dim3 g((nq + 255) / 256, Cout);
        if (S == 1)
            conv3x3<1><<<g, b256, 0, stream>>>(X, W, B, Y, Cin, Hin, Win, Hout, Wout);
        else
            conv3x3<2><<<g, b256, 0, stream>>>(X, W, B, Y, Cin, Hin, Win, Hout, Wout);
    };

    // Q path (padded, stride 1): 2048 -> 1024 -> 256 -> 256, spatial 32x64
    pad_rw<<<dim3(9, 2048), b256, 0, stream>>>(x, xpad);
    conv(xpad, qw1, qb1, q1, 2048, 1024, 34, 66, 32, 64, 1);
    pad_rw<<<dim3(9, 1024), b256, 0, stream>>>(q1, q1p);
    conv(q1p, qw2, qb2, q2, 1024, 256, 34, 66, 32, 64, 1);
    pad_rw<<<dim3(9, 256), b256, 0, stream>>>(q2, q2p);
    conv(q2p, qw3, qb3, q3, 256, 256, 34, 66, 32, 64, 1);

    // K path (VALID, strides 2,2,1): 32x64 -> 15x31 -> 7x15 -> 5x13
    conv(x,  kw1, kb1, k1, 2048, 1024, 32, 64, 15, 31, 2);
    conv(k1, kw2, kb2, k2, 1024, 256, 15, 31, 7, 15, 2);
    conv(k2, kw3, kb3, k3, 256, 256, 7, 15, 5, 13, 1);

    // V path (VALID, strides 2,2,1): -> (1024, 5, 13)
    conv(x,  vw1, vb1, v1, 2048, 1024, 32, 64, 15, 31, 2);
    conv(v1, vw2, vb2, v2, 1024, 1024, 15, 31, 7, 15, 2);
    conv(v2, vw3, vb3, v3, 1024, 1024, 7, 15, 5, 13, 1);

    // Attention: scores^T, softmax over query axis, o = V . beta^T
    qk_scores<<<dim3(8, 65), b256, 0, stream>>>(q3, k3, sT);
    softmax_n<<<65, 64, 0, stream>>>(sT, bT);
    attn_o<<<dim3(4, 1024), dim3(128), 0, stream>>>(v3, bT, o);

    // Final 1x1 conv + bias (no activation)
    conv1x1<<<dim3(4, 1024), dim3(128), 0, stream>>>(o, pw, pb, out);
}

// Round 6
// 4549.635 us; speedup vs baseline: 2.6224x; 2.6224x over previous
//
#include <hip/hip_runtime.h>
#include <cstdint>
#include <cstddef>

typedef __bf16 bf16x8 __attribute__((ext_vector_type(8)));
typedef __bf16 bf16x4 __attribute__((ext_vector_type(4)));
typedef float f32x4 __attribute__((ext_vector_type(4)));

#define LRELU(y) ((y) >= 0.f ? (y) : 0.3f * (y))

// ---------------------------------------------------------------------------
// async global->LDS 16B per lane. LDS dest is wave-uniform base + lane*16.
// ---------------------------------------------------------------------------
__device__ inline void gload_lds16(const void* g, void* lds) {
    auto gp = (const __attribute__((address_space(1))) uint32_t*)(uintptr_t)g;
    auto lp = (__attribute__((address_space(3))) uint32_t*)(uint32_t)(uintptr_t)lds;
    __builtin_amdgcn_global_load_lds(gp, lp, 16, 0, 0);
}

struct BfPair { __bf16 h, l; };
__device__ inline BfPair split2(float v) {
    BfPair p;
    p.h = (__bf16)v;
    p.l = (__bf16)(v - (float)p.h);
    return p;
}

// ---------------------------------------------------------------------------
// f32 -> bf16 hi/lo split (weights; count multiple of 4)
// ---------------------------------------------------------------------------
__global__ __launch_bounds__(256) void f2b2(const float4* __restrict__ in,
                                            bf16x4* __restrict__ oh,
                                            bf16x4* __restrict__ ol, int n4) {
    int i = blockIdx.x * 256 + threadIdx.x;
    if (i >= n4) return;
    float4 v = in[i];
    bf16x4 h, l;
    BfPair p;
    p = split2(v.x); h[0] = p.h; l[0] = p.l;
    p = split2(v.y); h[1] = p.h; l[1] = p.l;
    p = split2(v.z); h[2] = p.h; l[2] = p.l;
    p = split2(v.w); h[3] = p.h; l[3] = p.l;
    oh[i] = h; ol[i] = l;
}

// ---------------------------------------------------------------------------
// im2col, transposed, hi/lo bf16: dst[r][k] = X[ci][iy][ix], k = ci*9+tap.
// reflect-H / wrap-W padding (PAD=1), stride S, zero-fill rows n >= N.
// ---------------------------------------------------------------------------
__global__ __launch_bounds__(256) void im2col2(const float* __restrict__ src,
                                               __bf16* __restrict__ dh,
                                               __bf16* __restrict__ dl,
                                               int srcStride, int Hin, int Win,
                                               int Wout, int S, int PAD,
                                               int N, int n0, int nChunk, int K) {
    int kq = K >> 2;
    int tid = blockIdx.x * 256 + threadIdx.x;
    if (tid >= nChunk * kq) return;
    int r = tid / kq;
    int k0 = (tid - r * kq) << 2;
    int n = n0 + r;
    bf16x4 oh, ol;
    if (n >= N) {
#pragma unroll
        for (int j = 0; j < 4; ++j) { oh[j] = (__bf16)0.f; ol[j] = (__bf16)0.f; }
    } else {
        int oy = n / Wout, ox = n - oy * Wout;
#pragma unroll
        for (int j = 0; j < 4; ++j) {
            int k = k0 + j;
            int ci = k / 9, tap = k - ci * 9;
            int dy = tap / 3, dx = tap - dy * 3;
            int iy, ix;
            if (PAD) {
                iy = oy + dy - 1;
                iy = (iy == -1) ? 1 : (iy == Hin ? Hin - 2 : iy);
                ix = ox + dx - 1;
                ix = (ix < 0) ? ix + Win : (ix >= Win ? ix - Win : ix);
            } else {
                iy = oy * S + dy;
                ix = ox * S + dx;
            }
            BfPair p = split2(src[(size_t)ci * srcStride + iy * Win + ix]);
            oh[j] = p.h; ol[j] = p.l;
        }
    }
    *(bf16x4*)(dh + (size_t)r * K + k0) = oh;
    *(bf16x4*)(dl + (size_t)r * K + k0) = ol;
}

// ---------------------------------------------------------------------------
// Split-precision MFMA GEMM:
//   C = act( Ah*Bh^T + Ah*Bl^T + Al*Bh^T + bias )   (error ~2^-17 relative)
// 64x64 tile, 4 waves (2x2), BK=32, 16x16x32 MFMA, double-buffered LDS.
// C/D layout (m89-verified): row = 4*(lane>>4)+reg, col = lane&15.
// ---------------------------------------------------------------------------
template <bool RELU>
__global__ __launch_bounds__(256) void gemm_bt3(const __bf16* __restrict__ Ah,
                                                const __bf16* __restrict__ Al,
                                                const __bf16* __restrict__ Bh,
                                                const __bf16* __restrict__ Bl,
                                                const float* __restrict__ bias,
                                                float* __restrict__ C,
                                                int K, int Ldc, int n0) {
    __shared__ alignas(16) __bf16 sAh[2][4][64][8], sAl[2][4][64][8];
    __shared__ alignas(16) __bf16 sBh[2][4][64][8], sBl[2][4][64][8];

    const int tid = threadIdx.x;
    const int lane = tid & 63;
    const int wave = tid >> 6;
    const int l15 = lane & 15;
    const int hi = lane >> 4;
    const int wm32 = ((wave >> 1) & 1) * 32;
    const int wn32 = (wave & 1) * 32;
    const int m0 = blockIdx.y * 64;
    const int bx = blockIdx.x;

    const __bf16* gah = Ah + (size_t)(m0 + lane) * K + wave * 8;
    const __bf16* gal = Al + (size_t)(m0 + lane) * K + wave * 8;
    const __bf16* gbh = Bh + (size_t)(bx * 64 + lane) * K + wave * 8;
    const __bf16* gbl = Bl + (size_t)(bx * 64 + lane) * K + wave * 8;

    f32x4 acc00 = {0.f, 0.f, 0.f, 0.f}, acc01 = {0.f, 0.f, 0.f, 0.f};
    f32x4 acc10 = {0.f, 0.f, 0.f, 0.f}, acc11 = {0.f, 0.f, 0.f, 0.f};

    auto stage = [&](int buf) {
        gload_lds16(gah, &sAh[buf][wave][0][0]);
        gload_lds16(gal, &sAl[buf][wave][0][0]);
        gload_lds16(gbh, &sBh[buf][wave][0][0]);
        gload_lds16(gbl, &sBl[buf][wave][0][0]);
        gah += 32; gal += 32; gbh += 32; gbl += 32;
    };
    auto compute = [&](int buf) {
        bf16x8 a0h = *(const bf16x8*)(&sAh[buf][hi][wm32 + l15][0]);
        bf16x8 a1h = *(const bf16x8*)(&sAh[buf][hi][wm32 + 16 + l15][0]);
        bf16x8 a0l = *(const bf16x8*)(&sAl[buf][hi][wm32 + l15][0]);
        bf16x8 a1l = *(const bf16x8*)(&sAl[buf][hi][wm32 + 16 + l15][0]);
        bf16x8 b0h = *(const bf16x8*)(&sBh[buf][hi][wn32 + l15][0]);
        bf16x8 b1h = *(const bf16x8*)(&sBh[buf][hi][wn32 + 16 + l15][0]);
        bf16x8 b0l = *(const bf16x8*)(&sBl[buf][hi][wn32 + l15][0]);
        bf16x8 b1l = *(const bf16x8*)(&sBl[buf][hi][wn32 + 16 + l15][0]);
        // hi*hi
        acc00 = __builtin_amdgcn_mfma_f32_16x16x32_bf16(a0h, b0h, acc00, 0, 0, 0);
        acc01 = __builtin_amdgcn_mfma_f32_16x16x32_bf16(a0h, b1h, acc01, 0, 0, 0);
        acc10 = __builtin_amdgcn_mfma_f32_16x16x32_bf16(a1h, b0h, acc10, 0, 0, 0);
        acc11 = __builtin_amdgcn_mfma_f32_16x16x32_bf16(a1h, b1h, acc11, 0, 0, 0);
        // hi*lo
        acc00 = __builtin_amdgcn_mfma_f32_16x16x32_bf16(a0h, b0l, acc00, 0, 0, 0);
        acc01 = __builtin_amdgcn_mfma_f32_16x16x32_bf16(a0h, b1l, acc01, 0, 0, 0);
        acc10 = __builtin_amdgcn_mfma_f32_16x16x32_bf16(a1h, b0l, acc10, 0, 0, 0);
        acc11 = __builtin_amdgcn_mfma_f32_16x16x32_bf16(a1h, b1l, acc11, 0, 0, 0);
        // lo*hi
        acc00 = __builtin_amdgcn_mfma_f32_16x16x32_bf16(a0l, b0h, acc00, 0, 0, 0);
        acc01 = __builtin_amdgcn_mfma_f32_16x16x32_bf16(a0l, b1h, acc01, 0, 0, 0);
        acc10 = __builtin_amdgcn_mfma_f32_16x16x32_bf16(a1l, b0h, acc10, 0, 0, 0);
        acc11 = __builtin_amdgcn_mfma_f32_16x16x32_bf16(a1l, b1h, acc11, 0, 0, 0);
    };

    const int NT = K >> 5;
    stage(0);
    __syncthreads();
    int cur = 0;
    for (int t = 0; t < NT - 1; ++t) {
        stage(cur ^ 1);
        compute(cur);
        __syncthreads();
        cur ^= 1;
    }
    compute(cur);

    const int row0 = m0 + wm32 + 4 * hi;
    const int col0 = n0 + bx * 64 + wn32 + l15;
    auto wr = [&](f32x4 acc, int mt, int nt) {
        int r0 = row0 + mt * 16;
        int c = col0 + nt * 16;
#pragma unroll
        for (int r = 0; r < 4; ++r) {
            float y = acc[r] + bias[r0 + r];
            if (RELU) y = LRELU(y);
            C[(size_t)(r0 + r) * Ldc + c] = y;
        }
    };
    wr(acc00, 0, 0); wr(acc01, 0, 1); wr(acc10, 1, 0); wr(acc11, 1, 1);
}

// ---------------------------------------------------------------------------
// scores^T: sT[m][n] = sum_c Q[c][n] * K[c][m]   (Q: 256x2048, K: 256x128pad)
// ---------------------------------------------------------------------------
__global__ __launch_bounds__(256) void qk_scores(const float* __restrict__ Q,
                                                 const float* __restrict__ K,
                                                 float* __restrict__ ST) {
    int m = blockIdx.y;
    int n = blockIdx.x * blockDim.x + threadIdx.x;
    float acc = 0.f;
    for (int c = 0; c < 256; ++c)
        acc += Q[c * 2048 + n] * K[c * 128 + m];
    ST[(size_t)m * 2048 + n] = acc;
}

// ---------------------------------------------------------------------------
// Softmax over n (2048) for each m. One wave per m.
// ---------------------------------------------------------------------------
__global__ __launch_bounds__(64) void softmax_n(const float* __restrict__ ST,
                                                float* __restrict__ BT) {
    int m = blockIdx.x;
    int lane = threadIdx.x;
    const float* s = ST + (size_t)m * 2048;
    float mx = -1e30f;
    for (int i = lane; i < 2048; i += 64) mx = fmaxf(mx, s[i]);
#pragma unroll
    for (int o = 32; o > 0; o >>= 1) mx = fmaxf(mx, __shfl_xor(mx, o, 64));
    float sum = 0.f;
    for (int i = lane; i < 2048; i += 64) sum += expf(s[i] - mx);
#pragma unroll
    for (int o = 32; o > 0; o >>= 1) sum += __shfl_xor(sum, o, 64);
    float inv = 1.f / sum;
    float* b = BT + (size_t)m * 2048;
    for (int i = lane; i < 2048; i += 64) b[i] = expf(s[i] - mx) * inv;
}

// ---------------------------------------------------------------------------
// o[v][n] = sum_m V[v][m] * BT[m][n]   (V: 1024x128pad, BT: 65x2048)
// ---------------------------------------------------------------------------
__global__ __launch_bounds__(128) void attn_o(const float* __restrict__ V,
                                              const float* __restrict__ BT,
                                              float* __restrict__ O) {
    int v = blockIdx.y;
    int n4 = (blockIdx.x * blockDim.x + threadIdx.x) * 4;
    float4 acc = {0.f, 0.f, 0.f, 0.f};
    for (int m = 0; m < 65; ++m) {
        float vv = V[v * 128 + m];
        float4 bb = *(const float4*)(BT + (size_t)m * 2048 + n4);
        acc.x += vv * bb.x;
        acc.y += vv * bb.y;
        acc.z += vv * bb.z;
        acc.w += vv * bb.w;
    }
    *(float4*)(O + (size_t)v * 2048 + n4) = acc;
}

// ---------------------------------------------------------------------------
// Transpose o [1024][2048] f32 -> ot hi/lo [2048][1024] bf16 (final 1x1 GEMM)
// ---------------------------------------------------------------------------
__global__ __launch_bounds__(256) void transp_b2(const float* __restrict__ o,
                                                 __bf16* __restrict__ oth,
                                                 __bf16* __restrict__ otl) {
    __shared__ float t[32][33];
    int tx = threadIdx.x & 31, ty = threadIdx.x >> 5;
    int n0 = blockIdx.x * 32, v0 = blockIdx.y * 32;
#pragma unroll
    for (int r = 0; r < 32; r += 8)
        t[ty + r][tx] = o[(size_t)(v0 + ty + r) * 2048 + n0 + tx];
    __syncthreads();
#pragma unroll
    for (int r = 0; r < 32; r += 8) {
        BfPair p = split2(t[tx][ty + r]);
        oth[(size_t)(n0 + ty + r) * 1024 + v0 + tx] = p.h;
        otl[(size_t)(n0 + ty + r) * 1024 + v0 + tx] = p.l;
    }
}

// ---------------------------------------------------------------------------
extern "C" void kernel_launch(void* const* d_in, const int* in_sizes, int n_in,
                              void* d_out, int out_size, void* d_ws, size_t ws_size,
                              hipStream_t stream) {
    (void)in_sizes; (void)n_in; (void)out_size; (void)ws_size;
    const float* x   = (const float*)d_in[0];
    const float* qw1 = (const float*)d_in[1];
    const float* qb1 = (const float*)d_in[2];
    const float* qw2 = (const float*)d_in[3];
    const float* qb2 = (const float*)d_in[4];
    const float* qw3 = (const float*)d_in[5];
    const float* qb3 = (const float*)d_in[6];
    const float* kw1 = (const float*)d_in[7];
    const float* kb1 = (const float*)d_in[8];
    const float* kw2 = (const float*)d_in[9];
    const float* kb2 = (const float*)d_in[10];
    const float* kw3 = (const float*)d_in[11];
    const float* kb3 = (const float*)d_in[12];
    const float* vw1 = (const float*)d_in[13];
    const float* vb1 = (const float*)d_in[14];
    const float* vw2 = (const float*)d_in[15];
    const float* vb2 = (const float*)d_in[16];
    const float* vw3 = (const float*)d_in[17];
    const float* vb3 = (const float*)d_in[18];
    const float* pw  = (const float*)d_in[19];
    const float* pb  = (const float*)d_in[20];
    float* out = (float*)d_out;

    float* ws = (float*)d_ws;
    size_t off = 0;
    auto alloc = [&](size_t nfloats) {
        float* p = ws + off;
        off += (nfloats + 63) & ~(size_t)63;  // 256B align
        return p;
    };
    const size_t WCAP = 18874368;  // bf16 elems: max weight = 1024*18432
    const size_t BCAP = 9437184;   // bf16 elems: B chunk capacity
    __bf16* WHI = (__bf16*)alloc(WCAP / 2);
    __bf16* WLO = (__bf16*)alloc(WCAP / 2);
    __bf16* BHI = (__bf16*)alloc(BCAP / 2);
    __bf16* BLO = (__bf16*)alloc(BCAP / 2);
    float* q1b = alloc((size_t)1024 * 2048);
    float* q2b = alloc((size_t)256 * 2048);
    float* q3b = alloc((size_t)256 * 2048);
    float* k1b = alloc((size_t)1024 * 512);
    float* k2b = alloc((size_t)256 * 128);
    float* k3b = alloc((size_t)256 * 128);
    float* v1b = alloc((size_t)1024 * 512);
    float* v2b = alloc((size_t)1024 * 128);
    float* v3b = alloc((size_t)1024 * 128);
    float* sT  = alloc((size_t)65 * 2048);
    float* bT  = alloc((size_t)65 * 2048);
    float* ob  = alloc((size_t)1024 * 2048);
    __bf16* oth = (__bf16*)alloc((size_t)1024 * 1024);
    __bf16* otl = (__bf16*)alloc((size_t)1024 * 1024);

    auto cdiv = [](size_t a, size_t b) { return (int)((a + b - 1) / b); };

    auto gemm3 = [&](const __bf16* Ah, const __bf16* Al, const __bf16* Bh,
                     const __bf16* Bl, const float* bias, float* C,
                     int M, int K, int Ldc, int n0, int nChunk, bool relu) {
        dim3 g(nChunk / 64, M / 64);
        if (relu)
            gemm_bt3<true><<<g, dim3(256), 0, stream>>>(Ah, Al, Bh, Bl, bias, C, K, Ldc, n0);
        else
            gemm_bt3<false><<<g, dim3(256), 0, stream>>>(Ah, Al, Bh, Bl, bias, C, K, Ldc, n0);
    };

    // one conv layer = f2b2(W) + per-chunk { im2col2 ; gemm3 }
    auto conv_mfma = [&](const float* src, int srcStride, int Hin, int Win,
                         int Hout, int Wout, int S, int PAD, int Cin,
                         const float* W, const float* b, int Cout,
                         float* outBuf, int Npad) {
        int K = Cin * 9, N = Hout * Wout;
        f2b2<<<cdiv((size_t)Cout * K / 4, 256), dim3(256), 0, stream>>>(
            (const float4*)W, (bf16x4*)WHI, (bf16x4*)WLO, Cout * K / 4);
        int chunk = (int)((BCAP / (size_t)K) & ~(size_t)63);
        if (chunk > Npad) chunk = Npad;
        for (int n0 = 0; n0 < Npad; n0 += chunk) {
            int nc = (Npad - n0 < chunk) ? (Npad - n0) : chunk;
            im2col2<<<cdiv((size_t)nc * K / 4, 256), dim3(256), 0, stream>>>(
                src, BHI, BLO, srcStride, Hin, Win, Wout, S, PAD, N, n0, nc, K);
            gemm3(WHI, WLO, BHI, BLO, b, outBuf, Cout, K, Npad, n0, nc, true);
        }
    };

    // Q path (reflect/wrap pad, stride 1), spatial 32x64 (N=2048)
    conv_mfma(x,   2048, 32, 64, 32, 64, 1, 1, 2048, qw1, qb1, 1024, q1b, 2048);
    conv_mfma(q1b, 2048, 32, 64, 32, 64, 1, 1, 1024, qw2, qb2, 256,  q2b, 2048);
    conv_mfma(q2b, 2048, 32, 64, 32, 64, 1, 1, 256,  qw3, qb3, 256,  q3b, 2048);

    // K path (VALID, strides 2,2,1): 32x64 -> 15x31(465->512) -> 7x15(105->128) -> 5x13(65->128)
    conv_mfma(x,   2048, 32, 64, 15, 31, 2, 0, 2048, kw1, kb1, 1024, k1b, 512);
    conv_mfma(k1b, 512,  15, 31, 7,  15, 2, 0, 1024, kw2, kb2, 256,  k2b, 128);
    conv_mfma(k2b, 128,  7,  15, 5,  13, 1, 0, 256,  kw3, kb3, 256,  k3b, 128);

    // V path
    conv_mfma(x,   2048, 32, 64, 15, 31, 2, 0, 2048, vw1, vb1, 1024, v1b, 512);
    conv_mfma(v1b, 512,  15, 31, 7,  15, 2, 0, 1024, vw2, vb2, 1024, v2b, 128);
    conv_mfma(v2b, 128,  7,  15, 5,  13, 1, 0, 1024, vw3, vb3, 1024, v3b, 128);

    // Attention (fp32): scores^T, softmax over query axis, o = V . beta^T
    qk_scores<<<dim3(8, 65), dim3(256), 0, stream>>>(q3b, k3b, sT);
    softmax_n<<<dim3(65), dim3(64), 0, stream>>>(sT, bT);
    attn_o<<<dim3(4, 1024), dim3(128), 0, stream>>>(v3b, bT, ob);

    // Final 1x1 conv via split GEMM: transpose o to bf16 hi/lo [n][v]
    transp_b2<<<dim3(64, 32), dim3(256), 0, stream>>>(ob, oth, otl);
    f2b2<<<cdiv((size_t)1024 * 1024 / 4, 256), dim3(256), 0, stream>>>(
        (const float4*)pw, (bf16x4*)WHI, (bf16x4*)WLO, 1024 * 1024 / 4);
    gemm3(WHI, WLO, oth, otl, pb, out, 1024, 1024, 2048, 0, 2048, false);
}